// Round 16
// baseline (323.613 us; speedup 1.0000x reference)
//
#include <hip/hip_runtime.h>

#define NN 50000
#define NE 800000
#define HD 128

typedef short short8 __attribute__((ext_vector_type(8)));
typedef float floatx4 __attribute__((ext_vector_type(4)));
typedef float floatx16 __attribute__((ext_vector_type(16)));

static __device__ __forceinline__ unsigned short f2bf(float f) {
    unsigned int u = __float_as_uint(f);
    unsigned int lsb = (u >> 16) & 1u;
    u += 0x7fffu + lsb;
    return (unsigned short)(u >> 16);
}

// HW packed f32->bf16 (RNE), 2 elems/instr; lo=src0, hi=src1.
static __device__ __forceinline__ short8 pack2(float4 a, float4 b) {
    union { unsigned int u[4]; short8 s; } r;
    asm("v_cvt_pk_bf16_f32 %0, %1, %2" : "=v"(r.u[0]) : "v"(a.x), "v"(a.y));
    asm("v_cvt_pk_bf16_f32 %0, %1, %2" : "=v"(r.u[1]) : "v"(a.z), "v"(a.w));
    asm("v_cvt_pk_bf16_f32 %0, %1, %2" : "=v"(r.u[2]) : "v"(b.x), "v"(b.y));
    asm("v_cvt_pk_bf16_f32 %0, %1, %2" : "=v"(r.u[3]) : "v"(b.z), "v"(b.w));
    return r.s;
}

static __device__ __forceinline__ floatx4 mfma16x16x32(short8 a, short8 b, floatx4 c) {
    asm("v_mfma_f32_16x16x32_bf16 %0, %1, %2, %0" : "+v"(c) : "v"(a), "v"(b));
    return c;
}

static __device__ __forceinline__ floatx16 mfma32x32x16(short8 a, short8 b, floatx16 c) {
    asm("v_mfma_f32_32x32x16_bf16 %0, %1, %2, %0" : "+v"(c) : "v"(a), "v"(b));
    return c;
}

// Hazard guards: inline-asm MFMA is invisible to LLVM's GCNHazardRecognizer.
#define NOPGUARD_INIT8(A) asm volatile("s_nop 3" \
  : "+v"(A[0]),"+v"(A[1]),"+v"(A[2]),"+v"(A[3]),"+v"(A[4]),"+v"(A[5]),"+v"(A[6]),"+v"(A[7]))
#define NOPGUARD8(A) asm volatile("s_nop 7\ns_nop 7" \
  : "+v"(A[0]),"+v"(A[1]),"+v"(A[2]),"+v"(A[3]),"+v"(A[4]),"+v"(A[5]),"+v"(A[6]),"+v"(A[7]))
#define NOPGUARD_INIT4x16(A) asm volatile("s_nop 7" \
  : "+v"(A[0]),"+v"(A[1]),"+v"(A[2]),"+v"(A[3]))
#define NOPGUARD4x16(A) asm volatile("s_nop 7\ns_nop 7\ns_nop 7" \
  : "+v"(A[0]),"+v"(A[1]),"+v"(A[2]),"+v"(A[3]))

// Wave-local LDS fence.
#define WAVE_LDS_FENCE() asm volatile("s_waitcnt lgkmcnt(0)" ::: "memory")

// ---------------- weight packing (same layouts as r15) ----------------
__global__ void pack_weights(const float* __restrict__ mW1, const float* __restrict__ mW2,
                             const float* __restrict__ uW1, const float* __restrict__ uW2,
                             unsigned short* __restrict__ W1q, unsigned short* __restrict__ W2q,
                             unsigned short* __restrict__ U1p, unsigned short* __restrict__ U2p) {
    int t = blockIdx.x * 256 + threadIdx.x;
    if (t < 40960) {
        int i = t;
        int j = i & 7, lane = (i >> 3) & 63, n = (i >> 9) & 3, s = i >> 11;
        int k = s * 16 + ((lane >> 5) << 3) + j;
        int c = n * 32 + (lane & 31);
        W1q[i] = f2bf((k < 291) ? mW1[k * 128 + c] : 0.0f);
    } else if (t < 57344) {
        int i = t - 40960;
        int j = i & 7, lane = (i >> 3) & 63, n = (i >> 9) & 3, s = i >> 11;
        int k = s * 16 + ((lane >> 5) << 3) + j;
        int c = n * 32 + (lane & 31);
        W2q[i] = f2bf(mW2[k * 128 + c]);
    } else if (t < 90112) {
        int i = t - 57344;
        int j = i & 7, lane = (i >> 3) & 63, n = (i >> 9) & 7, kk = i >> 12;
        int k = kk * 32 + ((lane >> 4) << 3) + j;
        int c = n * 16 + (lane & 15);
        U1p[i] = f2bf(uW1[k * 128 + c]);
    } else if (t < 106496) {
        int i = t - 90112;
        int j = i & 7, lane = (i >> 3) & 63, n = (i >> 9) & 7, kk = i >> 12;
        int k = kk * 32 + ((lane >> 4) << 3) + j;
        int c = n * 16 + (lane & 15);
        U2p[i] = f2bf(uW2[k * 128 + c]);
    }
}

// ---------------- fp32 -> bf16 cast (x at rest) ----------------
__global__ void cast_kernel(const float* __restrict__ in, unsigned short* __restrict__ out,
                            int n8) {
    int t = blockIdx.x * 256 + threadIdx.x;
    if (t < n8) {
        float4 a = *reinterpret_cast<const float4*>(in + (size_t)t * 8);
        float4 b = *reinterpret_cast<const float4*>(in + (size_t)t * 8 + 4);
        *reinterpret_cast<short8*>(out + (size_t)t * 8) = pack2(a, b);
    }
}

// ---------------- CSR build: hist -> scan -> scatter ----------------
__global__ void hist_kernel(const int* __restrict__ ei, int* __restrict__ counts) {
    int e = blockIdx.x * 256 + threadIdx.x;
    if (e < NE) atomicAdd(&counts[ei[NE + e]], 1);
}

__global__ __launch_bounds__(1024)
void scan1_kernel(const int* __restrict__ counts, int* __restrict__ partial,
                  int* __restrict__ bsum) {
    __shared__ int wsum[16];
    int tid = threadIdx.x;
    int gid = blockIdx.x * 1024 + tid;
    int lane = tid & 63, w = tid >> 6;
    int v = (gid < NN) ? counts[gid] : 0;
    int s = v;
    #pragma unroll
    for (int o = 1; o < 64; o <<= 1) { int t = __shfl_up(s, o); if (lane >= o) s += t; }
    if (lane == 63) wsum[w] = s;
    __syncthreads();
    if (w == 0 && lane < 16) {
        int t = wsum[lane];
        #pragma unroll
        for (int o = 1; o < 16; o <<= 1) { int u = __shfl_up(t, o); if (lane >= o) t += u; }
        wsum[lane] = t;
    }
    __syncthreads();
    int base = (w > 0) ? wsum[w - 1] : 0;
    if (gid < NN) partial[gid] = base + s - v;
    if (tid == 1023) bsum[blockIdx.x] = base + s;
}

__global__ void scan2_kernel(int* __restrict__ bsum, int n) {
    int lane = threadIdx.x;
    int v = (lane < n) ? bsum[lane] : 0;
    int s = v;
    #pragma unroll
    for (int o = 1; o < 64; o <<= 1) { int t = __shfl_up(s, o); if (lane >= o) s += t; }
    if (lane < n) bsum[lane] = s - v;
}

__global__ void scatter_kernel(const int* __restrict__ ei, const int* __restrict__ partial,
                               const int* __restrict__ bsum, int* __restrict__ cursor,
                               const float* __restrict__ cd, const float* __restrict__ ea,
                               unsigned int* __restrict__ epack,
                               uint2* __restrict__ relb,
                               unsigned short* __restrict__ eab) {
    int e = blockIdx.x * 256 + threadIdx.x;
    if (e < NE) {
        int d = ei[NE + e];
        int s = ei[e];
        int pos = partial[d] + bsum[d >> 10] + atomicAdd(&cursor[d], 1);
        epack[pos] = (unsigned int)s | ((unsigned int)d << 16);
        float r0 = cd[d * 3 + 0] - cd[s * 3 + 0];
        float r1 = cd[d * 3 + 1] - cd[s * 3 + 1];
        float r2 = cd[d * 3 + 2] - cd[s * 3 + 2];
        uint2 rr;
        asm("v_cvt_pk_bf16_f32 %0, %1, %2" : "=v"(rr.x) : "v"(r0), "v"(r1));
        asm("v_cvt_pk_bf16_f32 %0, %1, %2" : "=v"(rr.y) : "v"(r2), "v"(0.0f));
        relb[pos] = rr;
        const float* eap = ea + (size_t)e * 32;
        unsigned short* eo = eab + (size_t)pos * 32;
        #pragma unroll
        for (int q = 0; q < 4; ++q) {
            float4 a = *reinterpret_cast<const float4*>(eap + q * 8);
            float4 b = *reinterpret_cast<const float4*>(eap + q * 8 + 4);
            *reinterpret_cast<short8*>(eo + q * 8) = pack2(a, b);
        }
    }
}

// ---------------- message MLP: 32x32x16, column-split wave pairs ----------------
// 128 dst-sorted edges per block, 4 waves = 2 pairs. Each pair covers 64
// edges; within a pair, wave pw computes output cols pw*64..pw*64+63 (its 2
// N-blocks). Per-wave weight stream halves vs r15: 3.4 -> 1.7 KB/edge
// (msg was at ~51% of the L2 BW ceiling on weight re-reads).
// A-fragments: row=lane&31 per 32-edge tile, k-chunk=(lane>>5)*8.
// C/D: col=Nblk*32+(lane&31), row=(q&3)+8*(q>>2)+4*(lane>>5) [m74/m101].
__global__ __launch_bounds__(256, 4)
void msg_kernel(const unsigned short* __restrict__ xb, const unsigned short* __restrict__ eab,
                const unsigned int* __restrict__ epack, const uint2* __restrict__ relb,
                const unsigned short* __restrict__ W1q, const float* __restrict__ mb1,
                const unsigned short* __restrict__ W2q, const float* __restrict__ mb2,
                float* __restrict__ aggr) {
    __shared__ unsigned short sH[128 * 136];   // hidden tile, then bf16 out tile
    __shared__ int sDst[128];

    const int tid  = threadIdx.x;
    const int lane = tid & 63;
    const int wid  = tid >> 6;
    const int lr31 = lane & 31;
    const int half = lane >> 5;
    const int pair = wid >> 1;         // 0,1
    const int pw   = wid & 1;          // column half of this wave
    const int prow0 = pair * 64;       // pair's first row in the block tile
    const int ebase = blockIdx.x * 128 + prow0;

    // Two edge rows per lane (tiles t=0,1 within the pair).
    const unsigned short* xs[2];
    const unsigned short* xd[2];
    const unsigned short* epr[2];
    uint2 rr[2];
    #pragma unroll
    for (int t = 0; t < 2; ++t) {
        int er = t * 32 + lr31;
        unsigned int p = epack[ebase + er];
        int src = (int)(p & 0xFFFFu);
        int dst = (int)(p >> 16);
        if (pw == 0 && half == 0) sDst[prow0 + er] = dst;
        xs[t]  = xb + (size_t)src * 128 + half * 8;
        xd[t]  = xb + (size_t)dst * 128 + half * 8;
        epr[t] = eab + (size_t)(ebase + er) * 32 + half * 8;
        rr[t]  = relb[ebase + er];
    }

    const short8* w1 = reinterpret_cast<const short8*>(W1q);
    const short8* w2 = reinterpret_cast<const short8*>(W2q);

    // Layer 1: pair computes 64x128; this wave: 2 edge tiles x 2 N-blocks.
    floatx16 acc[4];   // [t*2+n]
    #pragma unroll
    for (int i = 0; i < 4; ++i)
        #pragma unroll
        for (int q = 0; q < 16; ++q) acc[i][q] = 0.0f;
    NOPGUARD_INIT4x16(acc);

    #pragma unroll
    for (int s = 0; s < 19; ++s) {
        short8 a0, a1;
        if (s < 8) {
            a0 = *reinterpret_cast<const short8*>(xs[0] + s * 16);
            a1 = *reinterpret_cast<const short8*>(xs[1] + s * 16);
        } else if (s < 16) {
            a0 = *reinterpret_cast<const short8*>(xd[0] + (s - 8) * 16);
            a1 = *reinterpret_cast<const short8*>(xd[1] + (s - 8) * 16);
        } else if (s < 18) {
            a0 = *reinterpret_cast<const short8*>(epr[0] + (s - 16) * 16);
            a1 = *reinterpret_cast<const short8*>(epr[1] + (s - 16) * 16);
        } else {
            union { unsigned int u[4]; short8 s8; } z0, z1;
            z0.u[0] = (half == 0) ? rr[0].x : 0u;
            z0.u[1] = (half == 0) ? rr[0].y : 0u;
            z0.u[2] = 0u; z0.u[3] = 0u;
            z1.u[0] = (half == 0) ? rr[1].x : 0u;
            z1.u[1] = (half == 0) ? rr[1].y : 0u;
            z1.u[2] = 0u; z1.u[3] = 0u;
            a0 = z0.s8; a1 = z1.s8;
        }
        const short8* wb = w1 + (s * 4 + pw * 2) * 64 + lane;
        short8 b0 = wb[0];
        short8 b1 = wb[64];
        acc[0] = mfma32x32x16(a0, b0, acc[0]);
        acc[1] = mfma32x32x16(a0, b1, acc[1]);
        acc[2] = mfma32x32x16(a1, b0, acc[2]);
        acc[3] = mfma32x32x16(a1, b1, acc[3]);
    }
    NOPGUARD4x16(acc);

    // bias + ReLU -> sH; this wave writes its 64 cols of the pair's 64 rows.
    #pragma unroll
    for (int t = 0; t < 2; ++t)
        #pragma unroll
        for (int n = 0; n < 2; ++n) {
            int col = pw * 64 + n * 32 + lr31;
            float bias = mb1[col];
            #pragma unroll
            for (int q = 0; q < 16; ++q) {
                int crow = (q & 3) + 8 * (q >> 2) + 4 * half;
                sH[(prow0 + t * 32 + crow) * 136 + col] =
                    f2bf(fmaxf(acc[t * 2 + n][q] + bias, 0.0f));
            }
        }
    __syncthreads();   // hidden tile complete (both waves of each pair)

    // Per-pair segment-head mask over 64 rows (computed by both waves).
    unsigned long long hm;
    {
        int r = prow0 + lane;
        bool head = (lane == 0) || (sDst[r] != sDst[r - 1]);
        hm = __ballot(head);
    }

    // Layer 2: K=128 over the pair's hidden rows; A cross-wave from sH.
    floatx16 acc2[4];
    #pragma unroll
    for (int i = 0; i < 4; ++i)
        #pragma unroll
        for (int q = 0; q < 16; ++q) acc2[i][q] = 0.0f;
    NOPGUARD_INIT4x16(acc2);

    #pragma unroll
    for (int s = 0; s < 8; ++s) {
        short8 a0 = *reinterpret_cast<const short8*>(&sH[(prow0 + lr31) * 136 + s * 16 + half * 8]);
        short8 a1 = *reinterpret_cast<const short8*>(&sH[(prow0 + 32 + lr31) * 136 + s * 16 + half * 8]);
        const short8* wb = w2 + (s * 4 + pw * 2) * 64 + lane;
        short8 b0 = wb[0];
        short8 b1 = wb[64];
        acc2[0] = mfma32x32x16(a0, b0, acc2[0]);
        acc2[1] = mfma32x32x16(a0, b1, acc2[1]);
        acc2[2] = mfma32x32x16(a1, b0, acc2[2]);
        acc2[3] = mfma32x32x16(a1, b1, acc2[3]);
    }
    NOPGUARD4x16(acc2);
    __syncthreads();   // all cross-wave sH reads drained before overwrite

    // bias -> bf16 out tile (same wave-owned cols).
    #pragma unroll
    for (int t = 0; t < 2; ++t)
        #pragma unroll
        for (int n = 0; n < 2; ++n) {
            int col = pw * 64 + n * 32 + lr31;
            float bias = mb2[col];
            #pragma unroll
            for (int q = 0; q < 16; ++q) {
                int crow = (q & 3) + 8 * (q >> 2) + 4 * half;
                sH[(prow0 + t * 32 + crow) * 136 + col] = f2bf(acc2[t * 2 + n][q] + bias);
            }
        }
    WAVE_LDS_FENCE();   // out-tile cols are wave-private: wave fence suffices

    // Per-pair bitmask segmented reduce; this wave covers col = pw*64 + lane.
    {
        const int col = pw * 64 + lane;
        unsigned long long m = hm;
        while (m) {
            int start = __ffsll((long long)m) - 1;
            unsigned long long m2 = m & (m - 1);
            int end = m2 ? (__ffsll((long long)m2) - 1) : 64;
            float sum = 0.0f;
            for (int r = start; r < end; ++r) {
                unsigned int u0 = sH[(prow0 + r) * 136 + col];
                sum += __uint_as_float(u0 << 16);
            }
            atomicAdd(&aggr[sDst[prow0 + start] * 128 + col], sum);
            m = m2;
        }
    }
}

// ---------------- node update MLP + residual + LayerNorm (unchanged) ----------------
__global__
void node_kernel(const unsigned short* __restrict__ xb, const float* __restrict__ x,
                 const float* __restrict__ aggr,
                 const unsigned short* __restrict__ U1p, const float* __restrict__ ub1,
                 const unsigned short* __restrict__ U2p, const float* __restrict__ ub2,
                 const float* __restrict__ gamma, const float* __restrict__ beta,
                 float* __restrict__ out) {
    __shared__ unsigned short sH[64 * 136];

    const int tid = threadIdx.x;
    const int lane = tid & 63;
    const int wid = tid >> 6;
    const int g = lane >> 4;
    const int lr = lane & 15;
    const int arow = wid * 16 + lr;
    const int n0 = blockIdx.x * 64;

    int nd0 = n0 + arow;
    int ndc0 = (nd0 < NN) ? nd0 : (NN - 1);

    const unsigned short* xp = xb + (size_t)ndc0 * 128 + g * 8;
    const float* ap = aggr + (size_t)ndc0 * 128 + g * 8;

    short8 af[8];
    float4 ta[8];
    #pragma unroll
    for (int kk = 0; kk < 4; ++kk) {
        af[kk] = *reinterpret_cast<const short8*>(xp + kk * 32);
        ta[2 * kk]     = *reinterpret_cast<const float4*>(ap + kk * 32);
        ta[2 * kk + 1] = *reinterpret_cast<const float4*>(ap + kk * 32 + 4);
    }
    #pragma unroll
    for (int kk = 0; kk < 4; ++kk)
        af[4 + kk] = pack2(ta[2 * kk], ta[2 * kk + 1]);

    floatx4 acc[8];
    #pragma unroll
    for (int n = 0; n < 8; ++n)
        #pragma unroll
        for (int r = 0; r < 4; ++r) acc[n][r] = 0.0f;
    NOPGUARD_INIT8(acc);

    #pragma unroll
    for (int kk = 0; kk < 8; ++kk) {
        const short8* wb = reinterpret_cast<const short8*>(U1p) + (kk * 8) * 64 + lane;
        #pragma unroll
        for (int n = 0; n < 8; ++n)
            acc[n] = mfma16x16x32(af[kk], wb[n * 64], acc[n]);
    }
    NOPGUARD8(acc);

    #pragma unroll
    for (int n = 0; n < 8; ++n) {
        float bias = ub1[n * 16 + lr];
        #pragma unroll
        for (int r = 0; r < 4; ++r) {
            int row = wid * 16 + g * 4 + r;
            sH[row * 136 + n * 16 + lr] = f2bf(fmaxf(acc[n][r] + bias, 0.0f));
        }
    }
    WAVE_LDS_FENCE();

    short8 a2[4];
    #pragma unroll
    for (int kk = 0; kk < 4; ++kk)
        a2[kk] = *reinterpret_cast<const short8*>(&sH[arow * 136 + kk * 32 + g * 8]);

    floatx4 acc2[8];
    #pragma unroll
    for (int n = 0; n < 8; ++n)
        #pragma unroll
        for (int r = 0; r < 4; ++r) acc2[n][r] = 0.0f;
    NOPGUARD_INIT8(acc2);

    #pragma unroll
    for (int kk = 0; kk < 4; ++kk) {
        const short8* wb = reinterpret_cast<const short8*>(U2p) + (kk * 8) * 64 + lane;
        #pragma unroll
        for (int n = 0; n < 8; ++n)
            acc2[n] = mfma16x16x32(a2[kk], wb[n * 64], acc2[n]);
    }
    NOPGUARD8(acc2);

    #pragma unroll
    for (int r = 0; r < 4; ++r) {
        int row = wid * 16 + g * 4 + r;
        int nd = n0 + row;
        int ndc = (nd < NN) ? nd : (NN - 1);
        float vals[8];
        float s1 = 0.0f, s2 = 0.0f;
        #pragma unroll
        for (int n = 0; n < 8; ++n) {
            int col = n * 16 + lr;
            float v = acc2[n][r] + ub2[col] + x[ndc * 128 + col];
            vals[n] = v;
            s1 += v;
            s2 += v * v;
        }
        #pragma unroll
        for (int m = 1; m < 16; m <<= 1) {
            s1 += __shfl_xor(s1, m);
            s2 += __shfl_xor(s2, m);
        }
        float mean = s1 * (1.0f / 128.0f);
        float var = s2 * (1.0f / 128.0f) - mean * mean;
        float inv = rsqrtf(var + 1e-5f);
        if (nd < NN) {
            #pragma unroll
            for (int n = 0; n < 8; ++n) {
                int col = n * 16 + lr;
                out[nd * 128 + col] = (vals[n] - mean) * inv * gamma[col] + beta[col];
            }
        }
    }
}

extern "C" void kernel_launch(void* const* d_in, const int* in_sizes, int n_in,
                              void* d_out, int out_size, void* d_ws, size_t ws_size,
                              hipStream_t stream) {
    const float* x     = (const float*)d_in[0];
    const int*   ei    = (const int*)d_in[1];
    const float* ea    = (const float*)d_in[2];
    const float* cd    = (const float*)d_in[3];
    const float* mW1   = (const float*)d_in[4];
    const float* mb1   = (const float*)d_in[5];
    const float* mW2   = (const float*)d_in[6];
    const float* mb2   = (const float*)d_in[7];
    const float* uW1   = (const float*)d_in[8];
    const float* ub1   = (const float*)d_in[9];
    const float* uW2   = (const float*)d_in[10];
    const float* ub2   = (const float*)d_in[11];
    const float* gamma = (const float*)d_in[12];
    const float* beta  = (const float*)d_in[13];
    float* out = (float*)d_out;

    char* ws = (char*)d_ws;
    unsigned short* W1q = (unsigned short*)(ws);                     // 81,920 B
    unsigned short* W2q = (unsigned short*)(ws + 81920);             // 32,768 B
    unsigned short* U1p = (unsigned short*)(ws + 114688);            // 65,536 B
    unsigned short* U2p = (unsigned short*)(ws + 180224);            // 32,768 B
    int* counts  = (int*)(ws + 212992);                              // 200,704 B
    int* cursor  = (int*)(ws + 413696);                              // 200,704 B (adjacent: one memset)
    int* partial = (int*)(ws + 614400);                              // 200,704 B
    int* bsum    = (int*)(ws + 815104);                              // 256 B
    unsigned int* epack = (unsigned int*)(ws + 815360);              // 3,200,000 B
    uint2* relb  = (uint2*)(ws + 4015360);                           // 6,400,000 B
    unsigned short* xbuf = (unsigned short*)(ws + 10415360);         // 12,800,000 B
    unsigned short* eabuf = (unsigned short*)(ws + 23215360);        // 51,200,000 B
    // total ws use: 74,415,360 B

    float* aggr = out;   // aggr lives in d_out (exactly NN*HD floats)

    hipMemsetAsync(counts, 0, (size_t)(614400 - 212992), stream);
    hipMemsetAsync(aggr, 0, (size_t)NN * HD * sizeof(float), stream);

    pack_weights<<<416, 256, 0, stream>>>(mW1, mW2, uW1, uW2, W1q, W2q, U1p, U2p);
    cast_kernel<<<(NN * HD / 8 + 255) / 256, 256, 0, stream>>>(x, xbuf, NN * HD / 8);
    hist_kernel<<<(NE + 255) / 256, 256, 0, stream>>>(ei, counts);
    scan1_kernel<<<(NN + 1023) / 1024, 1024, 0, stream>>>(counts, partial, bsum);
    scan2_kernel<<<1, 64, 0, stream>>>(bsum, (NN + 1023) / 1024);
    scatter_kernel<<<(NE + 255) / 256, 256, 0, stream>>>(ei, partial, bsum, cursor, cd, ea, epack, relb, eabuf);
    msg_kernel<<<NE / 128, 256, 0, stream>>>(xbuf, eabuf, epack, relb, W1q, mb1, W2q, mb2, aggr);
    node_kernel<<<(NN + 63) / 64, 256, 0, stream>>>(xbuf, x, aggr, U1p, ub1, U2p, ub2, gamma, beta, out);
}

// Round 17
// 314.414 us; speedup vs baseline: 1.0293x; 1.0293x over previous
//
#include <hip/hip_runtime.h>

#define NN 50000
#define NE 800000
#define HD 128

typedef short short8 __attribute__((ext_vector_type(8)));
typedef float floatx4 __attribute__((ext_vector_type(4)));
typedef float floatx16 __attribute__((ext_vector_type(16)));

static __device__ __forceinline__ unsigned short f2bf(float f) {
    unsigned int u = __float_as_uint(f);
    unsigned int lsb = (u >> 16) & 1u;
    u += 0x7fffu + lsb;
    return (unsigned short)(u >> 16);
}

// HW packed f32->bf16 (RNE), 2 elems/instr; lo=src0, hi=src1.
static __device__ __forceinline__ short8 pack2(float4 a, float4 b) {
    union { unsigned int u[4]; short8 s; } r;
    asm("v_cvt_pk_bf16_f32 %0, %1, %2" : "=v"(r.u[0]) : "v"(a.x), "v"(a.y));
    asm("v_cvt_pk_bf16_f32 %0, %1, %2" : "=v"(r.u[1]) : "v"(a.z), "v"(a.w));
    asm("v_cvt_pk_bf16_f32 %0, %1, %2" : "=v"(r.u[2]) : "v"(b.x), "v"(b.y));
    asm("v_cvt_pk_bf16_f32 %0, %1, %2" : "=v"(r.u[3]) : "v"(b.z), "v"(b.w));
    return r.s;
}

static __device__ __forceinline__ floatx4 mfma16x16x32(short8 a, short8 b, floatx4 c) {
    asm("v_mfma_f32_16x16x32_bf16 %0, %1, %2, %0" : "+v"(c) : "v"(a), "v"(b));
    return c;
}

static __device__ __forceinline__ floatx16 mfma32x32x16(short8 a, short8 b, floatx16 c) {
    asm("v_mfma_f32_32x32x16_bf16 %0, %1, %2, %0" : "+v"(c) : "v"(a), "v"(b));
    return c;
}

// Hazard guards: inline-asm MFMA is invisible to LLVM's GCNHazardRecognizer.
#define NOPGUARD_INIT8(A) asm volatile("s_nop 3" \
  : "+v"(A[0]),"+v"(A[1]),"+v"(A[2]),"+v"(A[3]),"+v"(A[4]),"+v"(A[5]),"+v"(A[6]),"+v"(A[7]))
#define NOPGUARD8(A) asm volatile("s_nop 7\ns_nop 7" \
  : "+v"(A[0]),"+v"(A[1]),"+v"(A[2]),"+v"(A[3]),"+v"(A[4]),"+v"(A[5]),"+v"(A[6]),"+v"(A[7]))
#define NOPGUARD_INIT4x16(A) asm volatile("s_nop 7" \
  : "+v"(A[0]),"+v"(A[1]),"+v"(A[2]),"+v"(A[3]))
#define NOPGUARD4x16(A) asm volatile("s_nop 7\ns_nop 7\ns_nop 7" \
  : "+v"(A[0]),"+v"(A[1]),"+v"(A[2]),"+v"(A[3]))

// Wave-local LDS fence.
#define WAVE_LDS_FENCE() asm volatile("s_waitcnt lgkmcnt(0)" ::: "memory")

// ---------------- weight packing (same layouts as r15) ----------------
__global__ void pack_weights(const float* __restrict__ mW1, const float* __restrict__ mW2,
                             const float* __restrict__ uW1, const float* __restrict__ uW2,
                             unsigned short* __restrict__ W1q, unsigned short* __restrict__ W2q,
                             unsigned short* __restrict__ U1p, unsigned short* __restrict__ U2p) {
    int t = blockIdx.x * 256 + threadIdx.x;
    if (t < 40960) {
        int i = t;
        int j = i & 7, lane = (i >> 3) & 63, n = (i >> 9) & 3, s = i >> 11;
        int k = s * 16 + ((lane >> 5) << 3) + j;
        int c = n * 32 + (lane & 31);
        W1q[i] = f2bf((k < 291) ? mW1[k * 128 + c] : 0.0f);
    } else if (t < 57344) {
        int i = t - 40960;
        int j = i & 7, lane = (i >> 3) & 63, n = (i >> 9) & 3, s = i >> 11;
        int k = s * 16 + ((lane >> 5) << 3) + j;
        int c = n * 32 + (lane & 31);
        W2q[i] = f2bf(mW2[k * 128 + c]);
    } else if (t < 90112) {
        int i = t - 57344;
        int j = i & 7, lane = (i >> 3) & 63, n = (i >> 9) & 7, kk = i >> 12;
        int k = kk * 32 + ((lane >> 4) << 3) + j;
        int c = n * 16 + (lane & 15);
        U1p[i] = f2bf(uW1[k * 128 + c]);
    } else if (t < 106496) {
        int i = t - 90112;
        int j = i & 7, lane = (i >> 3) & 63, n = (i >> 9) & 7, kk = i >> 12;
        int k = kk * 32 + ((lane >> 4) << 3) + j;
        int c = n * 16 + (lane & 15);
        U2p[i] = f2bf(uW2[k * 128 + c]);
    }
}

// ---------------- fp32 -> bf16 cast (x at rest) ----------------
__global__ void cast_kernel(const float* __restrict__ in, unsigned short* __restrict__ out,
                            int n8) {
    int t = blockIdx.x * 256 + threadIdx.x;
    if (t < n8) {
        float4 a = *reinterpret_cast<const float4*>(in + (size_t)t * 8);
        float4 b = *reinterpret_cast<const float4*>(in + (size_t)t * 8 + 4);
        *reinterpret_cast<short8*>(out + (size_t)t * 8) = pack2(a, b);
    }
}

// ---------------- CSR build: hist -> scan -> scatter ----------------
__global__ void hist_kernel(const int* __restrict__ ei, int* __restrict__ counts) {
    int e = blockIdx.x * 256 + threadIdx.x;
    if (e < NE) atomicAdd(&counts[ei[NE + e]], 1);
}

__global__ __launch_bounds__(1024)
void scan1_kernel(const int* __restrict__ counts, int* __restrict__ partial,
                  int* __restrict__ bsum) {
    __shared__ int wsum[16];
    int tid = threadIdx.x;
    int gid = blockIdx.x * 1024 + tid;
    int lane = tid & 63, w = tid >> 6;
    int v = (gid < NN) ? counts[gid] : 0;
    int s = v;
    #pragma unroll
    for (int o = 1; o < 64; o <<= 1) { int t = __shfl_up(s, o); if (lane >= o) s += t; }
    if (lane == 63) wsum[w] = s;
    __syncthreads();
    if (w == 0 && lane < 16) {
        int t = wsum[lane];
        #pragma unroll
        for (int o = 1; o < 16; o <<= 1) { int u = __shfl_up(t, o); if (lane >= o) t += u; }
        wsum[lane] = t;
    }
    __syncthreads();
    int base = (w > 0) ? wsum[w - 1] : 0;
    if (gid < NN) partial[gid] = base + s - v;
    if (tid == 1023) bsum[blockIdx.x] = base + s;
}

__global__ void scan2_kernel(int* __restrict__ bsum, int n) {
    int lane = threadIdx.x;
    int v = (lane < n) ? bsum[lane] : 0;
    int s = v;
    #pragma unroll
    for (int o = 1; o < 64; o <<= 1) { int t = __shfl_up(s, o); if (lane >= o) s += t; }
    if (lane < n) bsum[lane] = s - v;
}

__global__ void scatter_kernel(const int* __restrict__ ei, const int* __restrict__ partial,
                               const int* __restrict__ bsum, int* __restrict__ cursor,
                               const float* __restrict__ cd, const float* __restrict__ ea,
                               unsigned int* __restrict__ epack,
                               uint2* __restrict__ relb,
                               unsigned short* __restrict__ eab) {
    int e = blockIdx.x * 256 + threadIdx.x;
    if (e < NE) {
        int d = ei[NE + e];
        int s = ei[e];
        int pos = partial[d] + bsum[d >> 10] + atomicAdd(&cursor[d], 1);
        epack[pos] = (unsigned int)s | ((unsigned int)d << 16);
        float r0 = cd[d * 3 + 0] - cd[s * 3 + 0];
        float r1 = cd[d * 3 + 1] - cd[s * 3 + 1];
        float r2 = cd[d * 3 + 2] - cd[s * 3 + 2];
        uint2 rr;
        asm("v_cvt_pk_bf16_f32 %0, %1, %2" : "=v"(rr.x) : "v"(r0), "v"(r1));
        asm("v_cvt_pk_bf16_f32 %0, %1, %2" : "=v"(rr.y) : "v"(r2), "v"(0.0f));
        relb[pos] = rr;
        const float* eap = ea + (size_t)e * 32;
        unsigned short* eo = eab + (size_t)pos * 32;
        #pragma unroll
        for (int q = 0; q < 4; ++q) {
            float4 a = *reinterpret_cast<const float4*>(eap + q * 8);
            float4 b = *reinterpret_cast<const float4*>(eap + q * 8 + 4);
            *reinterpret_cast<short8*>(eo + q * 8) = pack2(a, b);
        }
    }
}

// ---------------- message MLP: 32x32x16, column-split wave pairs (lean regs) ----------------
// 128 dst-sorted edges per block, 4 waves = 2 pairs; wave pw owns output cols
// pw*64..pw*64+63. Weight stream per edge halves vs r15 (weights were 6:1
// over gathers in L2 traffic). r16's regression was spill (WRITE +44MB at
// VGPR=64): fixed by (a) launch_bounds(256,3) -> ~170-reg budget with a
// waves-target BELOW current runtime occupancy (cannot squeeze), (b) 4x
// 32-bit byte-offsets against uniform SGPR bases instead of 6 live pointers,
// (c) straight-line k-phases instead of a branchy unified loop.
__global__ __launch_bounds__(256, 3)
void msg_kernel(const unsigned short* __restrict__ xb, const unsigned short* __restrict__ eab,
                const unsigned int* __restrict__ epack, const uint2* __restrict__ relb,
                const unsigned short* __restrict__ W1q, const float* __restrict__ mb1,
                const unsigned short* __restrict__ W2q, const float* __restrict__ mb2,
                float* __restrict__ aggr) {
    __shared__ unsigned short sH[128 * 136];   // hidden tile, then bf16 out tile
    __shared__ int sDst[128];

    const int tid  = threadIdx.x;
    const int lane = tid & 63;
    const int wid  = tid >> 6;
    const int lr31 = lane & 31;
    const int half = lane >> 5;
    const int pair = wid >> 1;
    const int pw   = wid & 1;
    const int prow0 = pair * 64;
    const int ebase = blockIdx.x * 128 + prow0;

    const char* xbb = (const char*)xb;
    const char* eabb = (const char*)eab;

    // Byte offsets for the two edge rows (tiles t=0,1) this wave consumes.
    unsigned int vo_s0, vo_d0, vo_s1, vo_d1;
    uint2 rr0, rr1;
    {
        unsigned int p0 = epack[ebase + lr31];
        unsigned int p1 = epack[ebase + 32 + lr31];
        int s0 = (int)(p0 & 0xFFFFu), d0 = (int)(p0 >> 16);
        int s1 = (int)(p1 & 0xFFFFu), d1 = (int)(p1 >> 16);
        if (pw == 0 && half == 0) {
            sDst[prow0 + lr31] = d0;
            sDst[prow0 + 32 + lr31] = d1;
        }
        vo_s0 = (unsigned int)s0 * 256u + (unsigned int)half * 16u;
        vo_d0 = (unsigned int)d0 * 256u + (unsigned int)half * 16u;
        vo_s1 = (unsigned int)s1 * 256u + (unsigned int)half * 16u;
        vo_d1 = (unsigned int)d1 * 256u + (unsigned int)half * 16u;
        rr0 = relb[ebase + lr31];
        rr1 = relb[ebase + 32 + lr31];
    }
    const unsigned int eo0 = (unsigned int)(ebase + lr31) * 64u + (unsigned int)half * 16u;
    const unsigned int eo1 = eo0 + 32u * 64u;

    const short8* w1 = reinterpret_cast<const short8*>(W1q);
    const short8* w2 = reinterpret_cast<const short8*>(W2q);

    floatx16 acc[4];   // [t*2+n]: t edge-tile, n N-subblock of this wave's half
    #pragma unroll
    for (int i = 0; i < 4; ++i)
        #pragma unroll
        for (int q = 0; q < 16; ++q) acc[i][q] = 0.0f;
    NOPGUARD_INIT4x16(acc);

#define L1_STEP(s_, A0_, A1_) do {                                          \
        const short8* wb_ = w1 + ((s_) * 4 + pw * 2) * 64 + lane;           \
        short8 b0_ = wb_[0];                                                \
        short8 b1_ = wb_[64];                                               \
        acc[0] = mfma32x32x16((A0_), b0_, acc[0]);                          \
        acc[1] = mfma32x32x16((A0_), b1_, acc[1]);                          \
        acc[2] = mfma32x32x16((A1_), b0_, acc[2]);                          \
        acc[3] = mfma32x32x16((A1_), b1_, acc[3]);                          \
    } while (0)

    // k 0..127: x_src
    #pragma unroll
    for (int s = 0; s < 8; ++s) {
        short8 a0 = *reinterpret_cast<const short8*>(xbb + vo_s0 + s * 32);
        short8 a1 = *reinterpret_cast<const short8*>(xbb + vo_s1 + s * 32);
        L1_STEP(s, a0, a1);
    }
    // k 128..255: x_dst
    #pragma unroll
    for (int s = 8; s < 16; ++s) {
        short8 a0 = *reinterpret_cast<const short8*>(xbb + vo_d0 + (s - 8) * 32);
        short8 a1 = *reinterpret_cast<const short8*>(xbb + vo_d1 + (s - 8) * 32);
        L1_STEP(s, a0, a1);
    }
    // k 256..287: edge_attr
    #pragma unroll
    for (int s = 16; s < 18; ++s) {
        short8 a0 = *reinterpret_cast<const short8*>(eabb + eo0 + (s - 16) * 32);
        short8 a1 = *reinterpret_cast<const short8*>(eabb + eo1 + (s - 16) * 32);
        L1_STEP(s, a0, a1);
    }
    // k 288..303: rel (half==0 lanes carry rel; k>=291 weights zero-padded).
    {
        union { unsigned int u[4]; short8 s8; } z0, z1;
        z0.u[0] = (half == 0) ? rr0.x : 0u;
        z0.u[1] = (half == 0) ? rr0.y : 0u;
        z0.u[2] = 0u; z0.u[3] = 0u;
        z1.u[0] = (half == 0) ? rr1.x : 0u;
        z1.u[1] = (half == 0) ? rr1.y : 0u;
        z1.u[2] = 0u; z1.u[3] = 0u;
        L1_STEP(18, z0.s8, z1.s8);
    }
#undef L1_STEP
    NOPGUARD4x16(acc);

    // bias + ReLU -> sH; this wave writes its 64 cols of the pair's 64 rows.
    #pragma unroll
    for (int t = 0; t < 2; ++t)
        #pragma unroll
        for (int n = 0; n < 2; ++n) {
            int col = pw * 64 + n * 32 + lr31;
            float bias = mb1[col];
            #pragma unroll
            for (int q = 0; q < 16; ++q) {
                int crow = (q & 3) + 8 * (q >> 2) + 4 * half;
                sH[(prow0 + t * 32 + crow) * 136 + col] =
                    f2bf(fmaxf(acc[t * 2 + n][q] + bias, 0.0f));
            }
        }
    __syncthreads();   // hidden tile complete (both waves of each pair)

    // Per-pair segment-head mask over 64 rows.
    unsigned long long hm;
    {
        int r = prow0 + lane;
        bool head = (lane == 0) || (sDst[r] != sDst[r - 1]);
        hm = __ballot(head);
    }

    // Layer 2: K=128 over the pair's hidden rows; A cross-wave from sH.
    floatx16 acc2[4];
    #pragma unroll
    for (int i = 0; i < 4; ++i)
        #pragma unroll
        for (int q = 0; q < 16; ++q) acc2[i][q] = 0.0f;
    NOPGUARD_INIT4x16(acc2);

    #pragma unroll
    for (int s = 0; s < 8; ++s) {
        short8 a0 = *reinterpret_cast<const short8*>(&sH[(prow0 + lr31) * 136 + s * 16 + half * 8]);
        short8 a1 = *reinterpret_cast<const short8*>(&sH[(prow0 + 32 + lr31) * 136 + s * 16 + half * 8]);
        const short8* wb = w2 + (s * 4 + pw * 2) * 64 + lane;
        short8 b0 = wb[0];
        short8 b1 = wb[64];
        acc2[0] = mfma32x32x16(a0, b0, acc2[0]);
        acc2[1] = mfma32x32x16(a0, b1, acc2[1]);
        acc2[2] = mfma32x32x16(a1, b0, acc2[2]);
        acc2[3] = mfma32x32x16(a1, b1, acc2[3]);
    }
    NOPGUARD4x16(acc2);
    __syncthreads();   // all cross-wave sH reads drained before overwrite

    // bias -> bf16 out tile (same wave-owned cols).
    #pragma unroll
    for (int t = 0; t < 2; ++t)
        #pragma unroll
        for (int n = 0; n < 2; ++n) {
            int col = pw * 64 + n * 32 + lr31;
            float bias = mb2[col];
            #pragma unroll
            for (int q = 0; q < 16; ++q) {
                int crow = (q & 3) + 8 * (q >> 2) + 4 * half;
                sH[(prow0 + t * 32 + crow) * 136 + col] = f2bf(acc2[t * 2 + n][q] + bias);
            }
        }
    WAVE_LDS_FENCE();   // out-tile cols are wave-private: wave fence suffices

    // Per-pair bitmask segmented reduce; this wave covers col = pw*64 + lane.
    {
        const int col = pw * 64 + lane;
        unsigned long long m = hm;
        while (m) {
            int start = __ffsll((long long)m) - 1;
            unsigned long long m2 = m & (m - 1);
            int end = m2 ? (__ffsll((long long)m2) - 1) : 64;
            float sum = 0.0f;
            for (int r = start; r < end; ++r) {
                unsigned int u0 = sH[(prow0 + r) * 136 + col];
                sum += __uint_as_float(u0 << 16);
            }
            atomicAdd(&aggr[sDst[prow0 + start] * 128 + col], sum);
            m = m2;
        }
    }
}

// ---------------- node update MLP + residual + LayerNorm (unchanged) ----------------
__global__
void node_kernel(const unsigned short* __restrict__ xb, const float* __restrict__ x,
                 const float* __restrict__ aggr,
                 const unsigned short* __restrict__ U1p, const float* __restrict__ ub1,
                 const unsigned short* __restrict__ U2p, const float* __restrict__ ub2,
                 const float* __restrict__ gamma, const float* __restrict__ beta,
                 float* __restrict__ out) {
    __shared__ unsigned short sH[64 * 136];

    const int tid = threadIdx.x;
    const int lane = tid & 63;
    const int wid = tid >> 6;
    const int g = lane >> 4;
    const int lr = lane & 15;
    const int arow = wid * 16 + lr;
    const int n0 = blockIdx.x * 64;

    int nd0 = n0 + arow;
    int ndc0 = (nd0 < NN) ? nd0 : (NN - 1);

    const unsigned short* xp = xb + (size_t)ndc0 * 128 + g * 8;
    const float* ap = aggr + (size_t)ndc0 * 128 + g * 8;

    short8 af[8];
    float4 ta[8];
    #pragma unroll
    for (int kk = 0; kk < 4; ++kk) {
        af[kk] = *reinterpret_cast<const short8*>(xp + kk * 32);
        ta[2 * kk]     = *reinterpret_cast<const float4*>(ap + kk * 32);
        ta[2 * kk + 1] = *reinterpret_cast<const float4*>(ap + kk * 32 + 4);
    }
    #pragma unroll
    for (int kk = 0; kk < 4; ++kk)
        af[4 + kk] = pack2(ta[2 * kk], ta[2 * kk + 1]);

    floatx4 acc[8];
    #pragma unroll
    for (int n = 0; n < 8; ++n)
        #pragma unroll
        for (int r = 0; r < 4; ++r) acc[n][r] = 0.0f;
    NOPGUARD_INIT8(acc);

    #pragma unroll
    for (int kk = 0; kk < 8; ++kk) {
        const short8* wb = reinterpret_cast<const short8*>(U1p) + (kk * 8) * 64 + lane;
        #pragma unroll
        for (int n = 0; n < 8; ++n)
            acc[n] = mfma16x16x32(af[kk], wb[n * 64], acc[n]);
    }
    NOPGUARD8(acc);

    #pragma unroll
    for (int n = 0; n < 8; ++n) {
        float bias = ub1[n * 16 + lr];
        #pragma unroll
        for (int r = 0; r < 4; ++r) {
            int row = wid * 16 + g * 4 + r;
            sH[row * 136 + n * 16 + lr] = f2bf(fmaxf(acc[n][r] + bias, 0.0f));
        }
    }
    WAVE_LDS_FENCE();

    short8 a2[4];
    #pragma unroll
    for (int kk = 0; kk < 4; ++kk)
        a2[kk] = *reinterpret_cast<const short8*>(&sH[arow * 136 + kk * 32 + g * 8]);

    floatx4 acc2[8];
    #pragma unroll
    for (int n = 0; n < 8; ++n)
        #pragma unroll
        for (int r = 0; r < 4; ++r) acc2[n][r] = 0.0f;
    NOPGUARD_INIT8(acc2);

    #pragma unroll
    for (int kk = 0; kk < 4; ++kk) {
        const short8* wb = reinterpret_cast<const short8*>(U2p) + (kk * 8) * 64 + lane;
        #pragma unroll
        for (int n = 0; n < 8; ++n)
            acc2[n] = mfma16x16x32(a2[kk], wb[n * 64], acc2[n]);
    }
    NOPGUARD8(acc2);

    #pragma unroll
    for (int r = 0; r < 4; ++r) {
        int row = wid * 16 + g * 4 + r;
        int nd = n0 + row;
        int ndc = (nd < NN) ? nd : (NN - 1);
        float vals[8];
        float s1 = 0.0f, s2 = 0.0f;
        #pragma unroll
        for (int n = 0; n < 8; ++n) {
            int col = n * 16 + lr;
            float v = acc2[n][r] + ub2[col] + x[ndc * 128 + col];
            vals[n] = v;
            s1 += v;
            s2 += v * v;
        }
        #pragma unroll
        for (int m = 1; m < 16; m <<= 1) {
            s1 += __shfl_xor(s1, m);
            s2 += __shfl_xor(s2, m);
        }
        float mean = s1 * (1.0f / 128.0f);
        float var = s2 * (1.0f / 128.0f) - mean * mean;
        float inv = rsqrtf(var + 1e-5f);
        if (nd < NN) {
            #pragma unroll
            for (int n = 0; n < 8; ++n) {
                int col = n * 16 + lr;
                out[nd * 128 + col] = (vals[n] - mean) * inv * gamma[col] + beta[col];
            }
        }
    }
}

extern "C" void kernel_launch(void* const* d_in, const int* in_sizes, int n_in,
                              void* d_out, int out_size, void* d_ws, size_t ws_size,
                              hipStream_t stream) {
    const float* x     = (const float*)d_in[0];
    const int*   ei    = (const int*)d_in[1];
    const float* ea    = (const float*)d_in[2];
    const float* cd    = (const float*)d_in[3];
    const float* mW1   = (const float*)d_in[4];
    const float* mb1   = (const float*)d_in[5];
    const float* mW2   = (const float*)d_in[6];
    const float* mb2   = (const float*)d_in[7];
    const float* uW1   = (const float*)d_in[8];
    const float* ub1   = (const float*)d_in[9];
    const float* uW2   = (const float*)d_in[10];
    const float* ub2   = (const float*)d_in[11];
    const float* gamma = (const float*)d_in[12];
    const float* beta  = (const float*)d_in[13];
    float* out = (float*)d_out;

    char* ws = (char*)d_ws;
    unsigned short* W1q = (unsigned short*)(ws);                     // 81,920 B
    unsigned short* W2q = (unsigned short*)(ws + 81920);             // 32,768 B
    unsigned short* U1p = (unsigned short*)(ws + 114688);            // 65,536 B
    unsigned short* U2p = (unsigned short*)(ws + 180224);            // 32,768 B
    int* counts  = (int*)(ws + 212992);                              // 200,704 B
    int* cursor  = (int*)(ws + 413696);                              // 200,704 B (adjacent: one memset)
    int* partial = (int*)(ws + 614400);                              // 200,704 B
    int* bsum    = (int*)(ws + 815104);                              // 256 B
    unsigned int* epack = (unsigned int*)(ws + 815360);              // 3,200,000 B
    uint2* relb  = (uint2*)(ws + 4015360);                           // 6,400,000 B
    unsigned short* xbuf = (unsigned short*)(ws + 10415360);         // 12,800,000 B
    unsigned short* eabuf = (unsigned short*)(ws + 23215360);        // 51,200,000 B
    // total ws use: 74,415,360 B

    float* aggr = out;   // aggr lives in d_out (exactly NN*HD floats)

    hipMemsetAsync(counts, 0, (size_t)(614400 - 212992), stream);
    hipMemsetAsync(aggr, 0, (size_t)NN * HD * sizeof(float), stream);

    pack_weights<<<416, 256, 0, stream>>>(mW1, mW2, uW1, uW2, W1q, W2q, U1p, U2p);
    cast_kernel<<<(NN * HD / 8 + 255) / 256, 256, 0, stream>>>(x, xbuf, NN * HD / 8);
    hist_kernel<<<(NE + 255) / 256, 256, 0, stream>>>(ei, counts);
    scan1_kernel<<<(NN + 1023) / 1024, 1024, 0, stream>>>(counts, partial, bsum);
    scan2_kernel<<<1, 64, 0, stream>>>(bsum, (NN + 1023) / 1024);
    scatter_kernel<<<(NE + 255) / 256, 256, 0, stream>>>(ei, partial, bsum, cursor, cd, ea, epack, relb, eabuf);
    msg_kernel<<<NE / 128, 256, 0, stream>>>(xbuf, eabuf, epack, relb, W1q, mb1, W2q, mb2, aggr);
    node_kernel<<<(NN + 63) / 64, 256, 0, stream>>>(xbuf, x, aggr, U1p, ub1, U2p, ub2, gamma, beta, out);
}

// Round 18
// 313.383 us; speedup vs baseline: 1.0326x; 1.0033x over previous
//
#include <hip/hip_runtime.h>

#define NN 50000
#define NE 800000
#define HD 128

typedef short short8 __attribute__((ext_vector_type(8)));
typedef float floatx4 __attribute__((ext_vector_type(4)));
typedef float floatx16 __attribute__((ext_vector_type(16)));

static __device__ __forceinline__ unsigned short f2bf(float f) {
    unsigned int u = __float_as_uint(f);
    unsigned int lsb = (u >> 16) & 1u;
    u += 0x7fffu + lsb;
    return (unsigned short)(u >> 16);
}

// HW packed f32->bf16 (RNE), 2 elems/instr; lo=src0, hi=src1.
static __device__ __forceinline__ short8 pack2(float4 a, float4 b) {
    union { unsigned int u[4]; short8 s; } r;
    asm("v_cvt_pk_bf16_f32 %0, %1, %2" : "=v"(r.u[0]) : "v"(a.x), "v"(a.y));
    asm("v_cvt_pk_bf16_f32 %0, %1, %2" : "=v"(r.u[1]) : "v"(a.z), "v"(a.w));
    asm("v_cvt_pk_bf16_f32 %0, %1, %2" : "=v"(r.u[2]) : "v"(b.x), "v"(b.y));
    asm("v_cvt_pk_bf16_f32 %0, %1, %2" : "=v"(r.u[3]) : "v"(b.z), "v"(b.w));
    return r.s;
}

static __device__ __forceinline__ floatx4 mfma16x16x32(short8 a, short8 b, floatx4 c) {
    asm("v_mfma_f32_16x16x32_bf16 %0, %1, %2, %0" : "+v"(c) : "v"(a), "v"(b));
    return c;
}

static __device__ __forceinline__ floatx16 mfma32x32x16(short8 a, short8 b, floatx16 c) {
    asm("v_mfma_f32_32x32x16_bf16 %0, %1, %2, %0" : "+v"(c) : "v"(a), "v"(b));
    return c;
}

// Hazard guards: inline-asm MFMA is invisible to LLVM's GCNHazardRecognizer.
// Ledger: register-based weight-reuse (r16/r17 column-split) closed -- the
// allocator pins this kernel at 64 VGPR and spills the excess. r15 structure
// (155us) is the base; this round shares weights via LDS instead (no per-
// thread register growth).
#define NOPGUARD_INIT8(A) asm volatile("s_nop 3" \
  : "+v"(A[0]),"+v"(A[1]),"+v"(A[2]),"+v"(A[3]),"+v"(A[4]),"+v"(A[5]),"+v"(A[6]),"+v"(A[7]))
#define NOPGUARD8(A) asm volatile("s_nop 7\ns_nop 7" \
  : "+v"(A[0]),"+v"(A[1]),"+v"(A[2]),"+v"(A[3]),"+v"(A[4]),"+v"(A[5]),"+v"(A[6]),"+v"(A[7]))
#define NOPGUARD_INIT4x16(A) asm volatile("s_nop 7" \
  : "+v"(A[0]),"+v"(A[1]),"+v"(A[2]),"+v"(A[3]))
#define NOPGUARD4x16(A) asm volatile("s_nop 7\ns_nop 7\ns_nop 7" \
  : "+v"(A[0]),"+v"(A[1]),"+v"(A[2]),"+v"(A[3]))

// Wave-local LDS fence.
#define WAVE_LDS_FENCE() asm volatile("s_waitcnt lgkmcnt(0)" ::: "memory")

// ---------------- weight packing (same layouts as r15) ----------------
__global__ void pack_weights(const float* __restrict__ mW1, const float* __restrict__ mW2,
                             const float* __restrict__ uW1, const float* __restrict__ uW2,
                             unsigned short* __restrict__ W1q, unsigned short* __restrict__ W2q,
                             unsigned short* __restrict__ U1p, unsigned short* __restrict__ U2p) {
    int t = blockIdx.x * 256 + threadIdx.x;
    if (t < 40960) {
        int i = t;
        int j = i & 7, lane = (i >> 3) & 63, n = (i >> 9) & 3, s = i >> 11;
        int k = s * 16 + ((lane >> 5) << 3) + j;
        int c = n * 32 + (lane & 31);
        W1q[i] = f2bf((k < 291) ? mW1[k * 128 + c] : 0.0f);
    } else if (t < 57344) {
        int i = t - 40960;
        int j = i & 7, lane = (i >> 3) & 63, n = (i >> 9) & 3, s = i >> 11;
        int k = s * 16 + ((lane >> 5) << 3) + j;
        int c = n * 32 + (lane & 31);
        W2q[i] = f2bf(mW2[k * 128 + c]);
    } else if (t < 90112) {
        int i = t - 57344;
        int j = i & 7, lane = (i >> 3) & 63, n = (i >> 9) & 7, kk = i >> 12;
        int k = kk * 32 + ((lane >> 4) << 3) + j;
        int c = n * 16 + (lane & 15);
        U1p[i] = f2bf(uW1[k * 128 + c]);
    } else if (t < 106496) {
        int i = t - 90112;
        int j = i & 7, lane = (i >> 3) & 63, n = (i >> 9) & 7, kk = i >> 12;
        int k = kk * 32 + ((lane >> 4) << 3) + j;
        int c = n * 16 + (lane & 15);
        U2p[i] = f2bf(uW2[k * 128 + c]);
    }
}

// ---------------- fp32 -> bf16 cast (x at rest) ----------------
__global__ void cast_kernel(const float* __restrict__ in, unsigned short* __restrict__ out,
                            int n8) {
    int t = blockIdx.x * 256 + threadIdx.x;
    if (t < n8) {
        float4 a = *reinterpret_cast<const float4*>(in + (size_t)t * 8);
        float4 b = *reinterpret_cast<const float4*>(in + (size_t)t * 8 + 4);
        *reinterpret_cast<short8*>(out + (size_t)t * 8) = pack2(a, b);
    }
}

// ---------------- CSR build: hist -> scan -> scatter ----------------
__global__ void hist_kernel(const int* __restrict__ ei, int* __restrict__ counts) {
    int e = blockIdx.x * 256 + threadIdx.x;
    if (e < NE) atomicAdd(&counts[ei[NE + e]], 1);
}

__global__ __launch_bounds__(1024)
void scan1_kernel(const int* __restrict__ counts, int* __restrict__ partial,
                  int* __restrict__ bsum) {
    __shared__ int wsum[16];
    int tid = threadIdx.x;
    int gid = blockIdx.x * 1024 + tid;
    int lane = tid & 63, w = tid >> 6;
    int v = (gid < NN) ? counts[gid] : 0;
    int s = v;
    #pragma unroll
    for (int o = 1; o < 64; o <<= 1) { int t = __shfl_up(s, o); if (lane >= o) s += t; }
    if (lane == 63) wsum[w] = s;
    __syncthreads();
    if (w == 0 && lane < 16) {
        int t = wsum[lane];
        #pragma unroll
        for (int o = 1; o < 16; o <<= 1) { int u = __shfl_up(t, o); if (lane >= o) t += u; }
        wsum[lane] = t;
    }
    __syncthreads();
    int base = (w > 0) ? wsum[w - 1] : 0;
    if (gid < NN) partial[gid] = base + s - v;
    if (tid == 1023) bsum[blockIdx.x] = base + s;
}

__global__ void scan2_kernel(int* __restrict__ bsum, int n) {
    int lane = threadIdx.x;
    int v = (lane < n) ? bsum[lane] : 0;
    int s = v;
    #pragma unroll
    for (int o = 1; o < 64; o <<= 1) { int t = __shfl_up(s, o); if (lane >= o) s += t; }
    if (lane < n) bsum[lane] = s - v;
}

__global__ void scatter_kernel(const int* __restrict__ ei, const int* __restrict__ partial,
                               const int* __restrict__ bsum, int* __restrict__ cursor,
                               const float* __restrict__ cd, const float* __restrict__ ea,
                               unsigned int* __restrict__ epack,
                               uint2* __restrict__ relb,
                               unsigned short* __restrict__ eab) {
    int e = blockIdx.x * 256 + threadIdx.x;
    if (e < NE) {
        int d = ei[NE + e];
        int s = ei[e];
        int pos = partial[d] + bsum[d >> 10] + atomicAdd(&cursor[d], 1);
        epack[pos] = (unsigned int)s | ((unsigned int)d << 16);
        float r0 = cd[d * 3 + 0] - cd[s * 3 + 0];
        float r1 = cd[d * 3 + 1] - cd[s * 3 + 1];
        float r2 = cd[d * 3 + 2] - cd[s * 3 + 2];
        uint2 rr;
        asm("v_cvt_pk_bf16_f32 %0, %1, %2" : "=v"(rr.x) : "v"(r0), "v"(r1));
        asm("v_cvt_pk_bf16_f32 %0, %1, %2" : "=v"(rr.y) : "v"(r2), "v"(0.0f));
        relb[pos] = rr;
        const float* eap = ea + (size_t)e * 32;
        unsigned short* eo = eab + (size_t)pos * 32;
        #pragma unroll
        for (int q = 0; q < 4; ++q) {
            float4 a = *reinterpret_cast<const float4*>(eap + q * 8);
            float4 b = *reinterpret_cast<const float4*>(eap + q * 8 + 4);
            *reinterpret_cast<short8*>(eo + q * 8) = pack2(a, b);
        }
    }
}

// ---------------- message MLP: r15 structure + LDS-shared weight chunks ----------------
// 128 dst-sorted edges per block (4 waves x 32), 32x32x16 MFMA. Each k-step's
// 4 KB weight chunk is staged once into LDS (thread tid copies 16 B, one
// chunk prefetched in a single short8 register) and ds_read by all 4 waves:
// L2 weight traffic drops 4x vs r15 (was ~51% of the L2 ceiling). 2 barriers
// per k-step = the m97-proven pattern.
__global__ __launch_bounds__(256, 4)
void msg_kernel(const unsigned short* __restrict__ xb, const unsigned short* __restrict__ eab,
                const unsigned int* __restrict__ epack, const uint2* __restrict__ relb,
                const unsigned short* __restrict__ W1q, const float* __restrict__ mb1,
                const float* __restrict__ mb2,
                float* __restrict__ aggr) {
    __shared__ unsigned short sH[128 * 136];   // hidden tile, then bf16 out tile
    __shared__ unsigned short sW[2048];        // one 4 KB weight chunk
    __shared__ int sDst[128];

    const int tid = threadIdx.x;
    const int lane = tid & 63;
    const int wid = tid >> 6;
    const int lr31 = lane & 31;
    const int half = lane >> 5;
    const int wrow = wid * 32 + lr31;
    const int eidx = blockIdx.x * 128 + wrow;

    const unsigned int p = epack[eidx];
    const int src = (int)(p & 0xFFFFu);
    const int dst = (int)(p >> 16);
    if (half == 0) sDst[wrow] = dst;

    const unsigned short* xs = xb + (size_t)src * 128 + half * 8;
    const unsigned short* xd = xb + (size_t)dst * 128 + half * 8;
    const unsigned short* epr = eab + (size_t)eidx * 32 + half * 8;
    const uint2 rr = relb[eidx];

    // Prefetch weight chunk 0 (L1). W2 chunks live at short-offset 40960
    // (W1q and W2q are contiguous in the workspace).
    short8 wpre = *reinterpret_cast<const short8*>(W1q + tid * 8);

    // Layer 1: (128x320) @ (320x128); per wave 32x128 = 4 x (32x32).
    floatx16 acc[4];
    #pragma unroll
    for (int n = 0; n < 4; ++n)
        #pragma unroll
        for (int q = 0; q < 16; ++q) acc[n][q] = 0.0f;
    NOPGUARD_INIT4x16(acc);

    #pragma unroll
    for (int s = 0; s < 19; ++s) {
        *reinterpret_cast<short8*>(sW + tid * 8) = wpre;
        __syncthreads();
        {   // prefetch next chunk: L1 s+1, or W2 chunk 0 after the last L1 step
            int nc = (s < 18) ? (s + 1) * 2048 : 40960;
            wpre = *reinterpret_cast<const short8*>(W1q + nc + tid * 8);
        }
        short8 a;
        if (s < 8) {
            a = *reinterpret_cast<const short8*>(xs + s * 16);
        } else if (s < 16) {
            a = *reinterpret_cast<const short8*>(xd + (s - 8) * 16);
        } else if (s < 18) {
            a = *reinterpret_cast<const short8*>(epr + (s - 16) * 16);
        } else {
            union { unsigned int u[4]; short8 s8; } a9;
            a9.u[0] = (half == 0) ? rr.x : 0u;
            a9.u[1] = (half == 0) ? rr.y : 0u;
            a9.u[2] = 0u; a9.u[3] = 0u;
            a = a9.s8;
        }
        #pragma unroll
        for (int n = 0; n < 4; ++n) {
            short8 b = *reinterpret_cast<const short8*>(sW + n * 512 + lane * 8);
            acc[n] = mfma32x32x16(a, b, acc[n]);
        }
        __syncthreads();
    }
    NOPGUARD4x16(acc);

    // Per-wave segment-head mask over this wave's 32 rows.
    unsigned int hm32;
    {
        bool head = false;
        if (lane < 32) {
            int r = wid * 32 + lane;
            head = (lane == 0) || (sDst[r] != sDst[r - 1]);
        }
        unsigned long long m = __ballot(head);
        hm32 = (unsigned int)(m & 0xFFFFFFFFull);
    }

    // bias + ReLU -> sH (bf16), wave-private 32-row slice.
    #pragma unroll
    for (int n = 0; n < 4; ++n) {
        float bias = mb1[n * 32 + lr31];
        #pragma unroll
        for (int q = 0; q < 16; ++q) {
            int crow = (q & 3) + 8 * (q >> 2) + 4 * half;
            sH[(wid * 32 + crow) * 136 + n * 32 + lr31] = f2bf(fmaxf(acc[n][q] + bias, 0.0f));
        }
    }
    WAVE_LDS_FENCE();

    // Layer 2: (128x128) @ (128x128), K=128 in 8 staged steps; A from sH.
    floatx16 acc2[4];
    #pragma unroll
    for (int n = 0; n < 4; ++n)
        #pragma unroll
        for (int q = 0; q < 16; ++q) acc2[n][q] = 0.0f;
    NOPGUARD_INIT4x16(acc2);

    #pragma unroll
    for (int s = 0; s < 8; ++s) {
        *reinterpret_cast<short8*>(sW + tid * 8) = wpre;
        __syncthreads();
        if (s < 7)
            wpre = *reinterpret_cast<const short8*>(W1q + 40960 + (s + 1) * 2048 + tid * 8);
        short8 a = *reinterpret_cast<const short8*>(&sH[wrow * 136 + s * 16 + half * 8]);
        #pragma unroll
        for (int n = 0; n < 4; ++n) {
            short8 b = *reinterpret_cast<const short8*>(sW + n * 512 + lane * 8);
            acc2[n] = mfma32x32x16(a, b, acc2[n]);
        }
        __syncthreads();
    }
    NOPGUARD4x16(acc2);
    WAVE_LDS_FENCE();   // wave's sH hidden reads drained before overwrite

    // bias -> bf16 LDS out tile (same wave-private rows).
    #pragma unroll
    for (int n = 0; n < 4; ++n) {
        float bias = mb2[n * 32 + lr31];
        #pragma unroll
        for (int q = 0; q < 16; ++q) {
            int crow = (q & 3) + 8 * (q >> 2) + 4 * half;
            sH[(wid * 32 + crow) * 136 + n * 32 + lr31] = f2bf(acc2[n][q] + bias);
        }
    }
    WAVE_LDS_FENCE();

    // Per-wave bitmask segmented reduce over 32 rows; lane covers cols
    // {lane, lane+64}; one atomic row per segment.
    {
        unsigned int m = hm32;
        while (m) {
            int start = __ffs(m) - 1;
            unsigned int m2 = m & (m - 1);
            int end = m2 ? (__ffs(m2) - 1) : 32;
            float sum0 = 0.0f, sum1 = 0.0f;
            for (int r = start; r < end; ++r) {
                int rw = wid * 32 + r;
                unsigned int u0 = sH[rw * 136 + lane];
                unsigned int u1 = sH[rw * 136 + 64 + lane];
                sum0 += __uint_as_float(u0 << 16);
                sum1 += __uint_as_float(u1 << 16);
            }
            int d = sDst[wid * 32 + start];
            atomicAdd(&aggr[d * 128 + lane], sum0);
            atomicAdd(&aggr[d * 128 + 64 + lane], sum1);
            m = m2;
        }
    }
}

// ---------------- node update MLP + residual + LayerNorm (unchanged) ----------------
__global__
void node_kernel(const unsigned short* __restrict__ xb, const float* __restrict__ x,
                 const float* __restrict__ aggr,
                 const unsigned short* __restrict__ U1p, const float* __restrict__ ub1,
                 const unsigned short* __restrict__ U2p, const float* __restrict__ ub2,
                 const float* __restrict__ gamma, const float* __restrict__ beta,
                 float* __restrict__ out) {
    __shared__ unsigned short sH[64 * 136];

    const int tid = threadIdx.x;
    const int lane = tid & 63;
    const int wid = tid >> 6;
    const int g = lane >> 4;
    const int lr = lane & 15;
    const int arow = wid * 16 + lr;
    const int n0 = blockIdx.x * 64;

    int nd0 = n0 + arow;
    int ndc0 = (nd0 < NN) ? nd0 : (NN - 1);

    const unsigned short* xp = xb + (size_t)ndc0 * 128 + g * 8;
    const float* ap = aggr + (size_t)ndc0 * 128 + g * 8;

    short8 af[8];
    float4 ta[8];
    #pragma unroll
    for (int kk = 0; kk < 4; ++kk) {
        af[kk] = *reinterpret_cast<const short8*>(xp + kk * 32);
        ta[2 * kk]     = *reinterpret_cast<const float4*>(ap + kk * 32);
        ta[2 * kk + 1] = *reinterpret_cast<const float4*>(ap + kk * 32 + 4);
    }
    #pragma unroll
    for (int kk = 0; kk < 4; ++kk)
        af[4 + kk] = pack2(ta[2 * kk], ta[2 * kk + 1]);

    floatx4 acc[8];
    #pragma unroll
    for (int n = 0; n < 8; ++n)
        #pragma unroll
        for (int r = 0; r < 4; ++r) acc[n][r] = 0.0f;
    NOPGUARD_INIT8(acc);

    #pragma unroll
    for (int kk = 0; kk < 8; ++kk) {
        const short8* wb = reinterpret_cast<const short8*>(U1p) + (kk * 8) * 64 + lane;
        #pragma unroll
        for (int n = 0; n < 8; ++n)
            acc[n] = mfma16x16x32(af[kk], wb[n * 64], acc[n]);
    }
    NOPGUARD8(acc);

    #pragma unroll
    for (int n = 0; n < 8; ++n) {
        float bias = ub1[n * 16 + lr];
        #pragma unroll
        for (int r = 0; r < 4; ++r) {
            int row = wid * 16 + g * 4 + r;
            sH[row * 136 + n * 16 + lr] = f2bf(fmaxf(acc[n][r] + bias, 0.0f));
        }
    }
    WAVE_LDS_FENCE();

    short8 a2[4];
    #pragma unroll
    for (int kk = 0; kk < 4; ++kk)
        a2[kk] = *reinterpret_cast<const short8*>(&sH[arow * 136 + kk * 32 + g * 8]);

    floatx4 acc2[8];
    #pragma unroll
    for (int n = 0; n < 8; ++n)
        #pragma unroll
        for (int r = 0; r < 4; ++r) acc2[n][r] = 0.0f;
    NOPGUARD_INIT8(acc2);

    #pragma unroll
    for (int kk = 0; kk < 4; ++kk) {
        const short8* wb = reinterpret_cast<const short8*>(U2p) + (kk * 8) * 64 + lane;
        #pragma unroll
        for (int n = 0; n < 8; ++n)
            acc2[n] = mfma16x16x32(a2[kk], wb[n * 64], acc2[n]);
    }
    NOPGUARD8(acc2);

    #pragma unroll
    for (int r = 0; r < 4; ++r) {
        int row = wid * 16 + g * 4 + r;
        int nd = n0 + row;
        int ndc = (nd < NN) ? nd : (NN - 1);
        float vals[8];
        float s1 = 0.0f, s2 = 0.0f;
        #pragma unroll
        for (int n = 0; n < 8; ++n) {
            int col = n * 16 + lr;
            float v = acc2[n][r] + ub2[col] + x[ndc * 128 + col];
            vals[n] = v;
            s1 += v;
            s2 += v * v;
        }
        #pragma unroll
        for (int m = 1; m < 16; m <<= 1) {
            s1 += __shfl_xor(s1, m);
            s2 += __shfl_xor(s2, m);
        }
        float mean = s1 * (1.0f / 128.0f);
        float var = s2 * (1.0f / 128.0f) - mean * mean;
        float inv = rsqrtf(var + 1e-5f);
        if (nd < NN) {
            #pragma unroll
            for (int n = 0; n < 8; ++n) {
                int col = n * 16 + lr;
                out[nd * 128 + col] = (vals[n] - mean) * inv * gamma[col] + beta[col];
            }
        }
    }
}

extern "C" void kernel_launch(void* const* d_in, const int* in_sizes, int n_in,
                              void* d_out, int out_size, void* d_ws, size_t ws_size,
                              hipStream_t stream) {
    const float* x     = (const float*)d_in[0];
    const int*   ei    = (const int*)d_in[1];
    const float* ea    = (const float*)d_in[2];
    const float* cd    = (const float*)d_in[3];
    const float* mW1   = (const float*)d_in[4];
    const float* mb1   = (const float*)d_in[5];
    const float* mW2   = (const float*)d_in[6];
    const float* mb2   = (const float*)d_in[7];
    const float* uW1   = (const float*)d_in[8];
    const float* ub1   = (const float*)d_in[9];
    const float* uW2   = (const float*)d_in[10];
    const float* ub2   = (const float*)d_in[11];
    const float* gamma = (const float*)d_in[12];
    const float* beta  = (const float*)d_in[13];
    float* out = (float*)d_out;

    char* ws = (char*)d_ws;
    unsigned short* W1q = (unsigned short*)(ws);                     // 81,920 B (W2q contiguous after)
    unsigned short* W2q = (unsigned short*)(ws + 81920);             // 32,768 B
    unsigned short* U1p = (unsigned short*)(ws + 114688);            // 65,536 B
    unsigned short* U2p = (unsigned short*)(ws + 180224);            // 32,768 B
    int* counts  = (int*)(ws + 212992);                              // 200,704 B
    int* cursor  = (int*)(ws + 413696);                              // 200,704 B (adjacent: one memset)
    int* partial = (int*)(ws + 614400);                              // 200,704 B
    int* bsum    = (int*)(ws + 815104);                              // 256 B
    unsigned int* epack = (unsigned int*)(ws + 815360);              // 3,200,000 B
    uint2* relb  = (uint2*)(ws + 4015360);                           // 6,400,000 B
    unsigned short* xbuf = (unsigned short*)(ws + 10415360);         // 12,800,000 B
    unsigned short* eabuf = (unsigned short*)(ws + 23215360);        // 51,200,000 B
    // total ws use: 74,415,360 B

    float* aggr = out;   // aggr lives in d_out (exactly NN*HD floats)

    hipMemsetAsync(counts, 0, (size_t)(614400 - 212992), stream);
    hipMemsetAsync(aggr, 0, (size_t)NN * HD * sizeof(float), stream);

    pack_weights<<<416, 256, 0, stream>>>(mW1, mW2, uW1, uW2, W1q, W2q, U1p, U2p);
    cast_kernel<<<(NN * HD / 8 + 255) / 256, 256, 0, stream>>>(x, xbuf, NN * HD / 8);
    hist_kernel<<<(NE + 255) / 256, 256, 0, stream>>>(ei, counts);
    scan1_kernel<<<(NN + 1023) / 1024, 1024, 0, stream>>>(counts, partial, bsum);
    scan2_kernel<<<1, 64, 0, stream>>>(bsum, (NN + 1023) / 1024);
    scatter_kernel<<<(NE + 255) / 256, 256, 0, stream>>>(ei, partial, bsum, cursor, cd, ea, epack, relb, eabuf);
    msg_kernel<<<NE / 128, 256, 0, stream>>>(xbuf, eabuf, epack, relb, W1q, mb1, mb2, aggr);
    node_kernel<<<(NN + 63) / 64, 256, 0, stream>>>(xbuf, x, aggr, U1p, ub1, U2p, ub2, gamma, beta, out);
}

// Round 19
// 276.883 us; speedup vs baseline: 1.1688x; 1.1318x over previous
//
#include <hip/hip_runtime.h>

#define NN 50000
#define NE 800000
#define HD 128

typedef short short8 __attribute__((ext_vector_type(8)));
typedef float floatx4 __attribute__((ext_vector_type(4)));
typedef float floatx16 __attribute__((ext_vector_type(16)));

static __device__ __forceinline__ unsigned short f2bf(float f) {
    unsigned int u = __float_as_uint(f);
    unsigned int lsb = (u >> 16) & 1u;
    u += 0x7fffu + lsb;
    return (unsigned short)(u >> 16);
}

// HW packed f32->bf16 (RNE), 2 elems/instr; lo=src0, hi=src1.
static __device__ __forceinline__ short8 pack2(float4 a, float4 b) {
    union { unsigned int u[4]; short8 s; } r;
    asm("v_cvt_pk_bf16_f32 %0, %1, %2" : "=v"(r.u[0]) : "v"(a.x), "v"(a.y));
    asm("v_cvt_pk_bf16_f32 %0, %1, %2" : "=v"(r.u[1]) : "v"(a.z), "v"(a.w));
    asm("v_cvt_pk_bf16_f32 %0, %1, %2" : "=v"(r.u[2]) : "v"(b.x), "v"(b.y));
    asm("v_cvt_pk_bf16_f32 %0, %1, %2" : "=v"(r.u[3]) : "v"(b.z), "v"(b.w));
    return r.s;
}

static __device__ __forceinline__ floatx4 mfma16x16x32(short8 a, short8 b, floatx4 c) {
    asm("v_mfma_f32_16x16x32_bf16 %0, %1, %2, %0" : "+v"(c) : "v"(a), "v"(b));
    return c;
}

static __device__ __forceinline__ floatx16 mfma32x32x16(short8 a, short8 b, floatx16 c) {
    asm("v_mfma_f32_32x32x16_bf16 %0, %1, %2, %0" : "+v"(c) : "v"(a), "v"(b));
    return c;
}

// Hazard guards: inline-asm MFMA is invisible to LLVM's GCNHazardRecognizer.
#define NOPGUARD_INIT8(A) asm volatile("s_nop 3" \
  : "+v"(A[0]),"+v"(A[1]),"+v"(A[2]),"+v"(A[3]),"+v"(A[4]),"+v"(A[5]),"+v"(A[6]),"+v"(A[7]))
#define NOPGUARD8(A) asm volatile("s_nop 7\ns_nop 7" \
  : "+v"(A[0]),"+v"(A[1]),"+v"(A[2]),"+v"(A[3]),"+v"(A[4]),"+v"(A[5]),"+v"(A[6]),"+v"(A[7]))
#define NOPGUARD_INIT4x16(A) asm volatile("s_nop 7" \
  : "+v"(A[0]),"+v"(A[1]),"+v"(A[2]),"+v"(A[3]))
#define NOPGUARD4x16(A) asm volatile("s_nop 7\ns_nop 7\ns_nop 7" \
  : "+v"(A[0]),"+v"(A[1]),"+v"(A[2]),"+v"(A[3]))

// Wave-local LDS fence.
#define WAVE_LDS_FENCE() asm volatile("s_waitcnt lgkmcnt(0)" ::: "memory")

// ---------------- weight packing (unchanged layouts) ----------------
__global__ void pack_weights(const float* __restrict__ mW1, const float* __restrict__ mW2,
                             const float* __restrict__ uW1, const float* __restrict__ uW2,
                             unsigned short* __restrict__ W1q, unsigned short* __restrict__ W2q,
                             unsigned short* __restrict__ U1p, unsigned short* __restrict__ U2p) {
    int t = blockIdx.x * 256 + threadIdx.x;
    if (t < 40960) {
        int i = t;
        int j = i & 7, lane = (i >> 3) & 63, n = (i >> 9) & 3, s = i >> 11;
        int k = s * 16 + ((lane >> 5) << 3) + j;
        int c = n * 32 + (lane & 31);
        W1q[i] = f2bf((k < 291) ? mW1[k * 128 + c] : 0.0f);
    } else if (t < 57344) {
        int i = t - 40960;
        int j = i & 7, lane = (i >> 3) & 63, n = (i >> 9) & 3, s = i >> 11;
        int k = s * 16 + ((lane >> 5) << 3) + j;
        int c = n * 32 + (lane & 31);
        W2q[i] = f2bf(mW2[k * 128 + c]);
    } else if (t < 90112) {
        int i = t - 57344;
        int j = i & 7, lane = (i >> 3) & 63, n = (i >> 9) & 7, kk = i >> 12;
        int k = kk * 32 + ((lane >> 4) << 3) + j;
        int c = n * 16 + (lane & 15);
        U1p[i] = f2bf(uW1[k * 128 + c]);
    } else if (t < 106496) {
        int i = t - 90112;
        int j = i & 7, lane = (i >> 3) & 63, n = (i >> 9) & 7, kk = i >> 12;
        int k = kk * 32 + ((lane >> 4) << 3) + j;
        int c = n * 16 + (lane & 15);
        U2p[i] = f2bf(uW2[k * 128 + c]);
    }
}

// ---------------- prep: fused x-cast + ea-cast (unsorted) + dst histogram ----------------
// Chunks 0..799,999 cast x (NN*HD/8 == NE, so the same threads do the hist
// atomics); chunks 800,000..3,999,999 cast ea. All reads/writes streaming.
__global__ void prep_kernel(const float* __restrict__ x, unsigned short* __restrict__ xbuf,
                            const float* __restrict__ ea, unsigned short* __restrict__ eabuf,
                            const int* __restrict__ ei, int* __restrict__ counts) {
    int t = blockIdx.x * 256 + threadIdx.x;
    if (t < 800000) {
        float4 a = *reinterpret_cast<const float4*>(x + (size_t)t * 8);
        float4 b = *reinterpret_cast<const float4*>(x + (size_t)t * 8 + 4);
        *reinterpret_cast<short8*>(xbuf + (size_t)t * 8) = pack2(a, b);
        atomicAdd(&counts[ei[NE + t]], 1);
    } else if (t < 4000000) {
        int u = t - 800000;
        float4 a = *reinterpret_cast<const float4*>(ea + (size_t)u * 8);
        float4 b = *reinterpret_cast<const float4*>(ea + (size_t)u * 8 + 4);
        *reinterpret_cast<short8*>(eabuf + (size_t)u * 8) = pack2(a, b);
    }
}

// ---------------- CSR scan (unchanged) ----------------
__global__ __launch_bounds__(1024)
void scan1_kernel(const int* __restrict__ counts, int* __restrict__ partial,
                  int* __restrict__ bsum) {
    __shared__ int wsum[16];
    int tid = threadIdx.x;
    int gid = blockIdx.x * 1024 + tid;
    int lane = tid & 63, w = tid >> 6;
    int v = (gid < NN) ? counts[gid] : 0;
    int s = v;
    #pragma unroll
    for (int o = 1; o < 64; o <<= 1) { int t = __shfl_up(s, o); if (lane >= o) s += t; }
    if (lane == 63) wsum[w] = s;
    __syncthreads();
    if (w == 0 && lane < 16) {
        int t = wsum[lane];
        #pragma unroll
        for (int o = 1; o < 16; o <<= 1) { int u = __shfl_up(t, o); if (lane >= o) t += u; }
        wsum[lane] = t;
    }
    __syncthreads();
    int base = (w > 0) ? wsum[w - 1] : 0;
    if (gid < NN) partial[gid] = base + s - v;
    if (tid == 1023) bsum[blockIdx.x] = base + s;
}

__global__ void scan2_kernel(int* __restrict__ bsum, int n) {
    int lane = threadIdx.x;
    int v = (lane < n) ? bsum[lane] : 0;
    int s = v;
    #pragma unroll
    for (int o = 1; o < 64; o <<= 1) { int t = __shfl_up(s, o); if (lane >= o) s += t; }
    if (lane < n) bsum[lane] = s - v;
}

// ---------------- scatter: epack64 (eid|src<<20|dst<<36) + bf16 rel only ----------------
// No ea pass, no 64B random writes: 16 MB total traffic.
__global__ void scatter_kernel(const int* __restrict__ ei, const int* __restrict__ partial,
                               const int* __restrict__ bsum, int* __restrict__ cursor,
                               const float* __restrict__ cd,
                               unsigned long long* __restrict__ epack,
                               uint2* __restrict__ relb) {
    int e = blockIdx.x * 256 + threadIdx.x;
    if (e < NE) {
        int d = ei[NE + e];
        int s = ei[e];
        int pos = partial[d] + bsum[d >> 10] + atomicAdd(&cursor[d], 1);
        epack[pos] = (unsigned long long)e
                   | ((unsigned long long)s << 20)
                   | ((unsigned long long)d << 36);
        float r0 = cd[d * 3 + 0] - cd[s * 3 + 0];
        float r1 = cd[d * 3 + 1] - cd[s * 3 + 1];
        float r2 = cd[d * 3 + 2] - cd[s * 3 + 2];
        uint2 rr;
        asm("v_cvt_pk_bf16_f32 %0, %1, %2" : "=v"(rr.x) : "v"(r0), "v"(r1));
        asm("v_cvt_pk_bf16_f32 %0, %1, %2" : "=v"(rr.y) : "v"(r2), "v"(0.0f));
        relb[pos] = rr;
    }
}

// ---------------- message MLP: r18 structure, ea gathered by eid ----------------
__global__ __launch_bounds__(256, 4)
void msg_kernel(const unsigned short* __restrict__ xb, const unsigned short* __restrict__ eab,
                const unsigned long long* __restrict__ epack, const uint2* __restrict__ relb,
                const unsigned short* __restrict__ W1q, const float* __restrict__ mb1,
                const float* __restrict__ mb2,
                float* __restrict__ aggr) {
    __shared__ unsigned short sH[128 * 136];   // hidden tile, then bf16 out tile
    __shared__ unsigned short sW[2048];        // one 4 KB weight chunk
    __shared__ int sDst[128];

    const int tid = threadIdx.x;
    const int lane = tid & 63;
    const int wid = tid >> 6;
    const int lr31 = lane & 31;
    const int half = lane >> 5;
    const int wrow = wid * 32 + lr31;
    const int eidx = blockIdx.x * 128 + wrow;

    const unsigned long long p = epack[eidx];
    const int eid = (int)(p & 0xFFFFFull);
    const int src = (int)((p >> 20) & 0xFFFFull);
    const int dst = (int)(p >> 36);
    if (half == 0) sDst[wrow] = dst;

    const unsigned short* xs = xb + (size_t)src * 128 + half * 8;
    const unsigned short* xd = xb + (size_t)dst * 128 + half * 8;
    const unsigned short* epr = eab + (size_t)eid * 32 + half * 8;
    const uint2 rr = relb[eidx];

    // Prefetch weight chunk 0 (W2 chunks contiguous at short-offset 40960).
    short8 wpre = *reinterpret_cast<const short8*>(W1q + tid * 8);

    // Layer 1: (128x320) @ (320x128); per wave 32x128 = 4 x (32x32).
    floatx16 acc[4];
    #pragma unroll
    for (int n = 0; n < 4; ++n)
        #pragma unroll
        for (int q = 0; q < 16; ++q) acc[n][q] = 0.0f;
    NOPGUARD_INIT4x16(acc);

    #pragma unroll
    for (int s = 0; s < 19; ++s) {
        *reinterpret_cast<short8*>(sW + tid * 8) = wpre;
        __syncthreads();
        {
            int nc = (s < 18) ? (s + 1) * 2048 : 40960;
            wpre = *reinterpret_cast<const short8*>(W1q + nc + tid * 8);
        }
        short8 a;
        if (s < 8) {
            a = *reinterpret_cast<const short8*>(xs + s * 16);
        } else if (s < 16) {
            a = *reinterpret_cast<const short8*>(xd + (s - 8) * 16);
        } else if (s < 18) {
            a = *reinterpret_cast<const short8*>(epr + (s - 16) * 16);
        } else {
            union { unsigned int u[4]; short8 s8; } a9;
            a9.u[0] = (half == 0) ? rr.x : 0u;
            a9.u[1] = (half == 0) ? rr.y : 0u;
            a9.u[2] = 0u; a9.u[3] = 0u;
            a = a9.s8;
        }
        #pragma unroll
        for (int n = 0; n < 4; ++n) {
            short8 b = *reinterpret_cast<const short8*>(sW + n * 512 + lane * 8);
            acc[n] = mfma32x32x16(a, b, acc[n]);
        }
        __syncthreads();
    }
    NOPGUARD4x16(acc);

    // Per-wave segment-head mask over this wave's 32 rows.
    unsigned int hm32;
    {
        bool head = false;
        if (lane < 32) {
            int r = wid * 32 + lane;
            head = (lane == 0) || (sDst[r] != sDst[r - 1]);
        }
        unsigned long long m = __ballot(head);
        hm32 = (unsigned int)(m & 0xFFFFFFFFull);
    }

    // bias + ReLU -> sH (bf16), wave-private 32-row slice.
    #pragma unroll
    for (int n = 0; n < 4; ++n) {
        float bias = mb1[n * 32 + lr31];
        #pragma unroll
        for (int q = 0; q < 16; ++q) {
            int crow = (q & 3) + 8 * (q >> 2) + 4 * half;
            sH[(wid * 32 + crow) * 136 + n * 32 + lr31] = f2bf(fmaxf(acc[n][q] + bias, 0.0f));
        }
    }
    WAVE_LDS_FENCE();

    // Layer 2: (128x128) @ (128x128), K=128 in 8 staged steps; A from sH.
    floatx16 acc2[4];
    #pragma unroll
    for (int n = 0; n < 4; ++n)
        #pragma unroll
        for (int q = 0; q < 16; ++q) acc2[n][q] = 0.0f;
    NOPGUARD_INIT4x16(acc2);

    #pragma unroll
    for (int s = 0; s < 8; ++s) {
        *reinterpret_cast<short8*>(sW + tid * 8) = wpre;
        __syncthreads();
        if (s < 7)
            wpre = *reinterpret_cast<const short8*>(W1q + 40960 + (s + 1) * 2048 + tid * 8);
        short8 a = *reinterpret_cast<const short8*>(&sH[wrow * 136 + s * 16 + half * 8]);
        #pragma unroll
        for (int n = 0; n < 4; ++n) {
            short8 b = *reinterpret_cast<const short8*>(sW + n * 512 + lane * 8);
            acc2[n] = mfma32x32x16(a, b, acc2[n]);
        }
        __syncthreads();
    }
    NOPGUARD4x16(acc2);
    WAVE_LDS_FENCE();

    // bias -> bf16 LDS out tile (same wave-private rows).
    #pragma unroll
    for (int n = 0; n < 4; ++n) {
        float bias = mb2[n * 32 + lr31];
        #pragma unroll
        for (int q = 0; q < 16; ++q) {
            int crow = (q & 3) + 8 * (q >> 2) + 4 * half;
            sH[(wid * 32 + crow) * 136 + n * 32 + lr31] = f2bf(acc2[n][q] + bias);
        }
    }
    WAVE_LDS_FENCE();

    // Per-wave bitmask segmented reduce over 32 rows; lane covers cols
    // {lane, lane+64}; one atomic row per segment.
    {
        unsigned int m = hm32;
        while (m) {
            int start = __ffs(m) - 1;
            unsigned int m2 = m & (m - 1);
            int end = m2 ? (__ffs(m2) - 1) : 32;
            float sum0 = 0.0f, sum1 = 0.0f;
            for (int r = start; r < end; ++r) {
                int rw = wid * 32 + r;
                unsigned int u0 = sH[rw * 136 + lane];
                unsigned int u1 = sH[rw * 136 + 64 + lane];
                sum0 += __uint_as_float(u0 << 16);
                sum1 += __uint_as_float(u1 << 16);
            }
            int d = sDst[wid * 32 + start];
            atomicAdd(&aggr[d * 128 + lane], sum0);
            atomicAdd(&aggr[d * 128 + 64 + lane], sum1);
            m = m2;
        }
    }
}

// ---------------- node update MLP + residual + LayerNorm (unchanged) ----------------
__global__
void node_kernel(const unsigned short* __restrict__ xb, const float* __restrict__ x,
                 const float* __restrict__ aggr,
                 const unsigned short* __restrict__ U1p, const float* __restrict__ ub1,
                 const unsigned short* __restrict__ U2p, const float* __restrict__ ub2,
                 const float* __restrict__ gamma, const float* __restrict__ beta,
                 float* __restrict__ out) {
    __shared__ unsigned short sH[64 * 136];

    const int tid = threadIdx.x;
    const int lane = tid & 63;
    const int wid = tid >> 6;
    const int g = lane >> 4;
    const int lr = lane & 15;
    const int arow = wid * 16 + lr;
    const int n0 = blockIdx.x * 64;

    int nd0 = n0 + arow;
    int ndc0 = (nd0 < NN) ? nd0 : (NN - 1);

    const unsigned short* xp = xb + (size_t)ndc0 * 128 + g * 8;
    const float* ap = aggr + (size_t)ndc0 * 128 + g * 8;

    short8 af[8];
    float4 ta[8];
    #pragma unroll
    for (int kk = 0; kk < 4; ++kk) {
        af[kk] = *reinterpret_cast<const short8*>(xp + kk * 32);
        ta[2 * kk]     = *reinterpret_cast<const float4*>(ap + kk * 32);
        ta[2 * kk + 1] = *reinterpret_cast<const float4*>(ap + kk * 32 + 4);
    }
    #pragma unroll
    for (int kk = 0; kk < 4; ++kk)
        af[4 + kk] = pack2(ta[2 * kk], ta[2 * kk + 1]);

    floatx4 acc[8];
    #pragma unroll
    for (int n = 0; n < 8; ++n)
        #pragma unroll
        for (int r = 0; r < 4; ++r) acc[n][r] = 0.0f;
    NOPGUARD_INIT8(acc);

    #pragma unroll
    for (int kk = 0; kk < 8; ++kk) {
        const short8* wb = reinterpret_cast<const short8*>(U1p) + (kk * 8) * 64 + lane;
        #pragma unroll
        for (int n = 0; n < 8; ++n)
            acc[n] = mfma16x16x32(af[kk], wb[n * 64], acc[n]);
    }
    NOPGUARD8(acc);

    #pragma unroll
    for (int n = 0; n < 8; ++n) {
        float bias = ub1[n * 16 + lr];
        #pragma unroll
        for (int r = 0; r < 4; ++r) {
            int row = wid * 16 + g * 4 + r;
            sH[row * 136 + n * 16 + lr] = f2bf(fmaxf(acc[n][r] + bias, 0.0f));
        }
    }
    WAVE_LDS_FENCE();

    short8 a2[4];
    #pragma unroll
    for (int kk = 0; kk < 4; ++kk)
        a2[kk] = *reinterpret_cast<const short8*>(&sH[arow * 136 + kk * 32 + g * 8]);

    floatx4 acc2[8];
    #pragma unroll
    for (int n = 0; n < 8; ++n)
        #pragma unroll
        for (int r = 0; r < 4; ++r) acc2[n][r] = 0.0f;
    NOPGUARD_INIT8(acc2);

    #pragma unroll
    for (int kk = 0; kk < 4; ++kk) {
        const short8* wb = reinterpret_cast<const short8*>(U2p) + (kk * 8) * 64 + lane;
        #pragma unroll
        for (int n = 0; n < 8; ++n)
            acc2[n] = mfma16x16x32(a2[kk], wb[n * 64], acc2[n]);
    }
    NOPGUARD8(acc2);

    #pragma unroll
    for (int r = 0; r < 4; ++r) {
        int row = wid * 16 + g * 4 + r;
        int nd = n0 + row;
        int ndc = (nd < NN) ? nd : (NN - 1);
        float vals[8];
        float s1 = 0.0f, s2 = 0.0f;
        #pragma unroll
        for (int n = 0; n < 8; ++n) {
            int col = n * 16 + lr;
            float v = acc2[n][r] + ub2[col] + x[ndc * 128 + col];
            vals[n] = v;
            s1 += v;
            s2 += v * v;
        }
        #pragma unroll
        for (int m = 1; m < 16; m <<= 1) {
            s1 += __shfl_xor(s1, m);
            s2 += __shfl_xor(s2, m);
        }
        float mean = s1 * (1.0f / 128.0f);
        float var = s2 * (1.0f / 128.0f) - mean * mean;
        float inv = rsqrtf(var + 1e-5f);
        if (nd < NN) {
            #pragma unroll
            for (int n = 0; n < 8; ++n) {
                int col = n * 16 + lr;
                out[nd * 128 + col] = (vals[n] - mean) * inv * gamma[col] + beta[col];
            }
        }
    }
}

extern "C" void kernel_launch(void* const* d_in, const int* in_sizes, int n_in,
                              void* d_out, int out_size, void* d_ws, size_t ws_size,
                              hipStream_t stream) {
    const float* x     = (const float*)d_in[0];
    const int*   ei    = (const int*)d_in[1];
    const float* ea    = (const float*)d_in[2];
    const float* cd    = (const float*)d_in[3];
    const float* mW1   = (const float*)d_in[4];
    const float* mb1   = (const float*)d_in[5];
    const float* mW2   = (const float*)d_in[6];
    const float* mb2   = (const float*)d_in[7];
    const float* uW1   = (const float*)d_in[8];
    const float* ub1   = (const float*)d_in[9];
    const float* uW2   = (const float*)d_in[10];
    const float* ub2   = (const float*)d_in[11];
    const float* gamma = (const float*)d_in[12];
    const float* beta  = (const float*)d_in[13];
    float* out = (float*)d_out;

    char* ws = (char*)d_ws;
    unsigned short* W1q = (unsigned short*)(ws);                     // 81,920 B (W2q contiguous after)
    unsigned short* W2q = (unsigned short*)(ws + 81920);             // 32,768 B
    unsigned short* U1p = (unsigned short*)(ws + 114688);            // 65,536 B
    unsigned short* U2p = (unsigned short*)(ws + 180224);            // 32,768 B
    int* counts  = (int*)(ws + 212992);                              // 200,704 B
    int* cursor  = (int*)(ws + 413696);                              // 200,704 B (adjacent: one memset)
    int* partial = (int*)(ws + 614400);                              // 200,704 B
    int* bsum    = (int*)(ws + 815104);                              // 256 B
    unsigned long long* epack = (unsigned long long*)(ws + 815360);  // 6,400,000 B
    uint2* relb  = (uint2*)(ws + 7215360);                           // 6,400,000 B
    unsigned short* xbuf = (unsigned short*)(ws + 13615360);         // 12,800,000 B
    unsigned short* eabuf = (unsigned short*)(ws + 26415360);        // 51,200,000 B (unsorted, by eid)
    // total ws use: 77,615,360 B (fits: r8 used the same)

    float* aggr = out;   // aggr lives in d_out (exactly NN*HD floats)

    hipMemsetAsync(counts, 0, (size_t)(614400 - 212992), stream);
    hipMemsetAsync(aggr, 0, (size_t)NN * HD * sizeof(float), stream);

    pack_weights<<<416, 256, 0, stream>>>(mW1, mW2, uW1, uW2, W1q, W2q, U1p, U2p);
    prep_kernel<<<(4000000 + 255) / 256, 256, 0, stream>>>(x, xbuf, ea, eabuf, ei, counts);
    scan1_kernel<<<(NN + 1023) / 1024, 1024, 0, stream>>>(counts, partial, bsum);
    scan2_kernel<<<1, 64, 0, stream>>>(bsum, (NN + 1023) / 1024);
    scatter_kernel<<<(NE + 255) / 256, 256, 0, stream>>>(ei, partial, bsum, cursor, cd, epack, relb);
    msg_kernel<<<NE / 128, 256, 0, stream>>>(xbuf, eabuf, epack, relb, W1q, mb1, mb2, aggr);
    node_kernel<<<(NN + 63) / 64, 256, 0, stream>>>(xbuf, x, aggr, U1p, ub1, U2p, ub2, gamma, beta, out);
}